// Round 6
// baseline (294332.642 us; speedup 1.0000x reference)
//
#include <hip/hip_runtime.h>
#include <math.h>

typedef unsigned short u16;
typedef unsigned int   u32;
typedef __attribute__((ext_vector_type(8))) short short8;
typedef __attribute__((ext_vector_type(4))) float f32x4;

#define HID  200
#define SEQT 128
#define NOUT 64
#define NTH  256
#define HST  200
#define PLN  ((size_t)4096*HST)
#define WSTR 228

// ---- LDS layout (bytes) ----
#define L_W  87552               // 6 planes * 32 rows * 228 * 2B
#define L_A  L_W                 // A staging dbuf starts here
#define CHB  28672               // one chunk: 4 sub-planes * 7168
#define L_G  (L_W + 2*CHB)       // 144896: gates dbuf [2][32][GRS] f32
#define GRS  66
#define L_TOT (L_G + 2*32*GRS*4) // 161792

// ---- workspace layout (bytes) ----
#define WS_PRED 0                // predG [4096] f32
#define WS_BAR  16384            // 8 groups * 64 u32
#define WS_H    18432            // 8 h planes (h1 x2 parity hi/lo, h2 x2)
#define WS_NEED (WS_H + 8*(int)(PLN*2) + 256)   // 13,125,888

// ---------------- helpers ----------------
__device__ __forceinline__ float fsig(float v) {
    return __builtin_amdgcn_rcpf(1.0f + __expf(-v));
}
__device__ __forceinline__ float ftanh(float v) {
    return 1.0f - 2.0f * __builtin_amdgcn_rcpf(__expf(2.0f * v) + 1.0f);
}
__device__ __forceinline__ u16 bf16_rne(float v) {
    u32 u = __float_as_uint(v);
    u = u + 0x7FFFu + ((u >> 16) & 1u);
    return (u16)(u >> 16);
}

__global__ void init_ws6(char* __restrict__ ws) {
    size_t n = WS_NEED / 4;
    u32* p = (u32*)ws;
    size_t str = (size_t)gridDim.x * blockDim.x;
    for (size_t i = (size_t)blockIdx.x * blockDim.x + threadIdx.x; i < n; i += str)
        p[i] = 0u;
}

// group barrier (32 WGs per group) via generation counter, agent scope
__device__ __forceinline__ void gbar(u32* barr, int g, unsigned& mygen) {
    __syncthreads();
    if (threadIdx.x == 0) {
        u32* cnt = barr + g * 64;
        u32* gen = barr + g * 64 + 32;
        unsigned target = mygen + 1;
        __threadfence();
        unsigned old = __hip_atomic_fetch_add(cnt, 1u, __ATOMIC_ACQ_REL, __HIP_MEMORY_SCOPE_AGENT);
        if (old == 31u) {
            __hip_atomic_store(cnt, 0u, __ATOMIC_RELAXED, __HIP_MEMORY_SCOPE_AGENT);
            __hip_atomic_fetch_add(gen, 1u, __ATOMIC_RELEASE, __HIP_MEMORY_SCOPE_AGENT);
        } else {
            while (__hip_atomic_load(gen, __ATOMIC_ACQUIRE, __HIP_MEMORY_SCOPE_AGENT) < target)
                __builtin_amdgcn_s_sleep(4);
        }
        __threadfence();
    }
    __syncthreads();
    mygen += 1;
}

// fp32 slice of 3 matrices -> bf16 hi/lo planes in LDS
__device__ __forceinline__ void load_weights(u16* Wl,
        const float* __restrict__ M0, const float* __restrict__ M1,
        const float* __restrict__ M2,
        int NRr, int cnt, int csh, int m0, int tid) {
    int tot = 3 * NRr * 224;
    for (int idx = tid; idx < tot; idx += NTH) {
        int k = idx % 224;
        int rem = idx / 224;
        int rr = rem % NRr;
        int mi = rem / NRr;
        const float* M = (mi == 0) ? M0 : ((mi == 1) ? M1 : M2);
        int n = 200 * (rr >> csh) + m0 + (rr & (cnt - 1));
        float v = (k < 200) ? M[n * 200 + k] : 0.0f;
        u16 hi = bf16_rne(v);
        float r2 = v - __uint_as_float(((u32)hi) << 16);
        u16 lo = bf16_rne(r2);
        Wl[(2 * mi) * (32 * WSTR) + rr * WSTR + k] = hi;
        Wl[(2 * mi + 1) * (32 * WSTR) + rr * WSTR + k] = lo;
    }
}

// async stage of one 16-row sub-plane (7168B) into LDS
__device__ __forceinline__ void stage_sub(char* dst, const u16* __restrict__ P,
                                          int row0, int lane) {
    const u16* g0 = P + (size_t)(row0 + (lane & 15)) * HST + ((lane >> 4) << 3);
#pragma unroll
    for (int c = 0; c < 7; ++c) {
        __builtin_amdgcn_global_load_lds(
            (const __attribute__((address_space(1))) u32*)(g0 + c * 32),
            (__attribute__((address_space(3))) u32*)(dst + c * 1024),
            16, 0, 0);
    }
}

__device__ __forceinline__ void loadB(const u16* Wl, int mp, int nt, int lane, short8* B) {
    const u16* bp = Wl + mp * (32 * WSTR) + (nt * 16 + (lane & 15)) * WSTR + ((lane >> 4) << 3);
#pragma unroll
    for (int c = 0; c < 7; ++c) B[c] = *(const short8*)(bp + c * 32);
}

// 3-term split-bf16 MFMA over c-range; two accs (even/odd c) break the dep chain
__device__ __forceinline__ void mmrange(const char* ab, int subhi,
        const short8* Bh, const short8* Bl, int c0, int c1, int lane,
        f32x4& e, f32x4& o) {
    const char* ah = ab + subhi * 7168;
    const char* al = ab + (subhi + 1) * 7168;
    for (int c = c0; c < c1; ++c) {
        short8 x = *(const short8*)(ah + c * 1024 + lane * 16);
        short8 y = *(const short8*)(al + c * 1024 + lane * 16);
        if (c & 1) {
            o = __builtin_amdgcn_mfma_f32_16x16x32_bf16(x, Bh[c], o, 0, 0, 0);
            o = __builtin_amdgcn_mfma_f32_16x16x32_bf16(x, Bl[c], o, 0, 0, 0);
            o = __builtin_amdgcn_mfma_f32_16x16x32_bf16(y, Bh[c], o, 0, 0, 0);
        } else {
            e = __builtin_amdgcn_mfma_f32_16x16x32_bf16(x, Bh[c], e, 0, 0, 0);
            e = __builtin_amdgcn_mfma_f32_16x16x32_bf16(x, Bl[c], e, 0, 0, 0);
            e = __builtin_amdgcn_mfma_f32_16x16x32_bf16(y, Bh[c], e, 0, 0, 0);
        }
    }
}

__device__ __forceinline__ void gwrite(float* gb, f32x4 e, f32x4 o,
        int rowbase, int sl, int slotw, int nt, int lane) {
    int rr = nt * 16 + (lane & 15);
    int r0 = rowbase + ((lane >> 4) << 2);
#pragma unroll
    for (int j = 0; j < 4; ++j) gb[(r0 + j) * GRS + sl * slotw + rr] = e[j] + o[j];
}

// elementwise: sum gate partial slots + bias (+x*wih), update c, write h hi/lo
__device__ __forceinline__ void ew_cell(const float* gb, float& cref,
    u16* __restrict__ Ohi, u16* __restrict__ Olo, int row0abs,
    int cnt, int csh, int m0, int nslots, int slotw,
    const float* __restrict__ bias, const float* __restrict__ wih,
    const float* __restrict__ psrc, int pstr, int poff, int tid)
{
    int row_l = tid >> csh, i = tid & (cnt - 1);
    int rowg = row0abs + row_l;
    float xv = 0.f;
    if (wih) xv = psrc[(size_t)rowg * pstr + poff];
    float v[4];
#pragma unroll
    for (int q = 0; q < 4; ++q) {
        int rr = q * cnt + i;
        float sacc = 0.f;
        for (int sl = 0; sl < nslots; ++sl) sacc += gb[row_l * GRS + sl * slotw + rr];
        int n = 200 * q + m0 + i;
        sacc += bias[n];
        if (wih) sacc = fmaf(xv, wih[n], sacc);
        v[q] = sacc;
    }
    float cn = fsig(v[1]) * cref + fsig(v[0]) * ftanh(v[2]);
    cref = cn;
    float h = fsig(v[3]) * ftanh(cn);
    u16 hv = bf16_rne(h);
    float r2 = h - __uint_as_float(((u32)hv) << 16);
    u16 lv = bf16_rne(r2);
    size_t ofs = (size_t)rowg * HST + m0 + i;
    Ohi[ofs] = hv;
    Olo[ofs] = lv;
}

// layer-1 cell: 16 chunks of 32 rows, pipelined
__device__ __forceinline__ void cell_l1(char* sm,
    const u16* Ahi, const u16* Alo, u16* Ohi, u16* Olo,
    const float* psrc, int pstr, int poff,
    const float* wih, const float* bias, float* c1,
    int heavy, int cnt, int csh, int m0, int b0g, int tid, int lane, int w)
{
    u16* Wl = (u16*)sm;
    char* Ab = sm + L_A;
    float* gb = (float*)(sm + L_G);
    short8 Bh[7], Bl[7];
    int nt = heavy ? (w & 1) : 0;
    loadB(Wl, 0, nt, lane, Bh);
    loadB(Wl, 1, nt, lane, Bl);
    int cA0, cA1, sl;
    if (heavy) { cA0 = (w >> 1) ? 4 : 0; cA1 = (w >> 1) ? 7 : 4; sl = w >> 1; }
    else { const int cs0[4] = {0, 2, 4, 6}; const int cs1[4] = {2, 4, 6, 7};
           cA0 = cs0[w]; cA1 = cs1[w]; sl = w; }
    int slotw = heavy ? 32 : 16;
    int nslots = heavy ? 2 : 4;
    const u16* SP = (w & 1) ? Alo : Ahi;
    int subrow = (w >> 1) << 4;
    int nact = 32 * cnt;

    stage_sub(Ab + w * 7168, SP, b0g + subrow, lane);
    asm volatile("s_waitcnt vmcnt(0)" ::: "memory");
    __syncthreads();
    for (int ch = 0; ch < 16; ++ch) {
        int pb = ch & 1;
        if (ch < 15)
            stage_sub(Ab + (pb ^ 1) * CHB + w * 7168, SP, b0g + (ch + 1) * 32 + subrow, lane);
        if (ch > 0 && tid < nact)
            ew_cell(gb + (pb ^ 1) * 32 * GRS, c1[ch - 1], Ohi, Olo, b0g + (ch - 1) * 32,
                    cnt, csh, m0, nslots, slotw, bias, wih, psrc, pstr, poff, tid);
        const char* ab = Ab + pb * CHB;
        f32x4 z = {0.f, 0.f, 0.f, 0.f};
        f32x4 e0 = z, o0 = z, e1 = z, o1 = z;
        mmrange(ab, 0, Bh, Bl, cA0, cA1, lane, e0, o0);
        mmrange(ab, 2, Bh, Bl, cA0, cA1, lane, e1, o1);
        float* gbp = gb + pb * 32 * GRS;
        gwrite(gbp, e0, o0, 0, sl, slotw, nt, lane);
        gwrite(gbp, e1, o1, 16, sl, slotw, nt, lane);
        asm volatile("s_waitcnt vmcnt(0)" ::: "memory");
        __syncthreads();
    }
    if (tid < nact)
        ew_cell(gb + 1 * 32 * GRS, c1[15], Ohi, Olo, b0g + 15 * 32,
                cnt, csh, m0, nslots, slotw, bias, wih, psrc, pstr, poff, tid);
}

// layer-2 cell: 32 chunks of 16 rows, A1(h1-new)+A2(h2-old) staged together
__device__ __forceinline__ void cell_l2(char* sm,
    const u16* A1hi, const u16* A1lo, const u16* A2hi, const u16* A2lo,
    u16* Ohi, u16* Olo, const float* bias, float* c2,
    int heavy, int cnt, int csh, int m0, int b0g, int tid, int lane, int w)
{
    u16* Wl = (u16*)sm;
    char* Ab = sm + L_A;
    float* gb = (float*)(sm + L_G);
    short8 Bh[7], Bl[7];
    int mat = w >> 1;
    int nt = heavy ? (w & 1) : 0;
    loadB(Wl, 2 + 2 * mat, nt, lane, Bh);
    loadB(Wl, 3 + 2 * mat, nt, lane, Bl);
    int cA0, cA1, sl;
    if (heavy) { cA0 = 0; cA1 = 7; sl = mat; }
    else { cA0 = (w & 1) ? 4 : 0; cA1 = (w & 1) ? 7 : 4; sl = w; }
    int slotw = heavy ? 32 : 16;
    int nslots = heavy ? 2 : 4;
    const u16* SP = (w < 2) ? ((w & 1) ? A1lo : A1hi) : ((w & 1) ? A2lo : A2hi);
    int nact = 16 * cnt;

    stage_sub(Ab + w * 7168, SP, b0g, lane);
    asm volatile("s_waitcnt vmcnt(0)" ::: "memory");
    __syncthreads();
    for (int ch = 0; ch < 32; ++ch) {
        int pb = ch & 1;
        if (ch < 31)
            stage_sub(Ab + (pb ^ 1) * CHB + w * 7168, SP, b0g + (ch + 1) * 16, lane);
        if (ch > 0 && tid < nact)
            ew_cell(gb + (pb ^ 1) * 32 * GRS, c2[ch - 1], Ohi, Olo, b0g + (ch - 1) * 16,
                    cnt, csh, m0, nslots, slotw, bias, nullptr, nullptr, 0, 0, tid);
        const char* ab = Ab + pb * CHB;
        f32x4 z = {0.f, 0.f, 0.f, 0.f};
        f32x4 e = z, o = z;
        mmrange(ab, 2 * mat, Bh, Bl, cA0, cA1, lane, e, o);
        gwrite(gb + pb * 32 * GRS, e, o, 0, sl, slotw, nt, lane);
        asm volatile("s_waitcnt vmcnt(0)" ::: "memory");
        __syncthreads();
    }
    if (tid < nact)
        ew_cell(gb + 1 * 32 * GRS, c2[31], Ohi, Olo, b0g + 31 * 16,
                cnt, csh, m0, nslots, slotw, bias, nullptr, nullptr, 0, 0, tid);
}

// decoder prediction: CU slice s handles 16 batch rows of its group
__device__ __forceinline__ void predp(float* ps,
    const u16* __restrict__ H2hi, const u16* __restrict__ H2lo,
    const float* __restrict__ linW, const float* __restrict__ linb,
    float* __restrict__ predG, float* __restrict__ out,
    int sd, int b0g, int s, int tid)
{
    int bi = tid >> 4, kk = tid & 15;
    float part = 0.f;
    size_t rb = (size_t)(b0g + s * 16 + bi) * HST;
#pragma unroll
    for (int j = 0; j < 13; ++j) {
        int k = kk + 16 * j;
        if (k < HID) {
            float hv = __uint_as_float(((u32)H2hi[rb + k]) << 16)
                     + __uint_as_float(((u32)H2lo[rb + k]) << 16);
            part = fmaf(hv, linW[k], part);
        }
    }
    ps[bi * 17 + kk] = part;
    __syncthreads();
    if (tid < 16) {
        float p = linb[0];
#pragma unroll
        for (int k2 = 0; k2 < 16; ++k2) p += ps[tid * 17 + k2];
        predG[b0g + s * 16 + tid] = p;
        out[(size_t)(b0g + s * 16 + tid) * NOUT + sd] = p;
    }
    __syncthreads();
}

__global__ __launch_bounds__(NTH, 1)
void lstm_v6(const float* __restrict__ x,
             const float* __restrict__ eWih0, const float* __restrict__ eWhh0,
             const float* __restrict__ eB0,
             const float* __restrict__ eWih1, const float* __restrict__ eWhh1,
             const float* __restrict__ eB1,
             const float* __restrict__ dWih0, const float* __restrict__ dWhh0,
             const float* __restrict__ dB0,
             const float* __restrict__ dWih1, const float* __restrict__ dWhh1,
             const float* __restrict__ dB1,
             const float* __restrict__ linW, const float* __restrict__ linb,
             u16* hb, float* predG, u32* barr, float* __restrict__ out)
{
    extern __shared__ char sm[];
    const int tid = threadIdx.x, lane = tid & 63, w = tid >> 6;
    const int g = blockIdx.x & 7, s = blockIdx.x >> 3;
    const int heavy = (s < 18) ? 1 : 0;
    const int cnt = heavy ? 8 : 4, csh = heavy ? 3 : 2;
    const int m0 = heavy ? 8 * s : 144 + 4 * (s - 18);
    const int b0g = g * 512;
    unsigned mygen = 0;

    load_weights((u16*)sm, eWhh0, eWih1, eWhh1, 4 * cnt, cnt, csh, m0, tid);
    __syncthreads();

    float c1[16], c2[32];
#pragma unroll
    for (int i = 0; i < 16; ++i) c1[i] = 0.f;
#pragma unroll
    for (int i = 0; i < 32; ++i) c2[i] = 0.f;
    int p1 = 0, p2 = 0;

    // ---------------- encoder ----------------
    for (int t = 0; t < SEQT; ++t) {
        cell_l1(sm, hb + (size_t)(2 * p1) * PLN, hb + (size_t)(2 * p1 + 1) * PLN,
                hb + (size_t)(2 * (p1 ^ 1)) * PLN, hb + (size_t)(2 * (p1 ^ 1) + 1) * PLN,
                x, SEQT, t, eWih0, eB0, c1,
                heavy, cnt, csh, m0, b0g, tid, lane, w);
        p1 ^= 1;
        gbar(barr, g, mygen);
        cell_l2(sm, hb + (size_t)(2 * p1) * PLN, hb + (size_t)(2 * p1 + 1) * PLN,
                hb + (size_t)(4 + 2 * p2) * PLN, hb + (size_t)(4 + 2 * p2 + 1) * PLN,
                hb + (size_t)(4 + 2 * (p2 ^ 1)) * PLN, hb + (size_t)(4 + 2 * (p2 ^ 1) + 1) * PLN,
                eB1, c2, heavy, cnt, csh, m0, b0g, tid, lane, w);
        p2 ^= 1;
    }

    // swap to decoder weights (CU-local)
    __syncthreads();
    load_weights((u16*)sm, dWhh0, dWih1, dWhh1, 4 * cnt, cnt, csh, m0, tid);
    __syncthreads();

    // ---------------- decoder ----------------
    for (int sd = 0; sd < NOUT; ++sd) {
        const float* psrc = (sd == 0) ? x : predG;
        int pstr = (sd == 0) ? SEQT : 1;
        int poff = (sd == 0) ? (SEQT - 1) : 0;
        cell_l1(sm, hb + (size_t)(2 * p1) * PLN, hb + (size_t)(2 * p1 + 1) * PLN,
                hb + (size_t)(2 * (p1 ^ 1)) * PLN, hb + (size_t)(2 * (p1 ^ 1) + 1) * PLN,
                psrc, pstr, poff, dWih0, dB0, c1,
                heavy, cnt, csh, m0, b0g, tid, lane, w);
        p1 ^= 1;
        gbar(barr, g, mygen);
        cell_l2(sm, hb + (size_t)(2 * p1) * PLN, hb + (size_t)(2 * p1 + 1) * PLN,
                hb + (size_t)(4 + 2 * p2) * PLN, hb + (size_t)(4 + 2 * p2 + 1) * PLN,
                hb + (size_t)(4 + 2 * (p2 ^ 1)) * PLN, hb + (size_t)(4 + 2 * (p2 ^ 1) + 1) * PLN,
                dB1, c2, heavy, cnt, csh, m0, b0g, tid, lane, w);
        p2 ^= 1;
        gbar(barr, g, mygen);
        predp((float*)(sm + L_G), hb + (size_t)(4 + 2 * p2) * PLN,
              hb + (size_t)(4 + 2 * p2 + 1) * PLN,
              linW, linb, predG, out, sd, b0g, s, tid);
        gbar(barr, g, mygen);
    }
}

extern "C" void kernel_launch(void* const* d_in, const int* in_sizes, int n_in,
                              void* d_out, int out_size, void* d_ws, size_t ws_size,
                              hipStream_t stream) {
    const float* x     = (const float*)d_in[0];
    const float* eWih0 = (const float*)d_in[1];
    const float* eWhh0 = (const float*)d_in[2];
    const float* eB0   = (const float*)d_in[3];
    const float* eWih1 = (const float*)d_in[4];
    const float* eWhh1 = (const float*)d_in[5];
    const float* eB1   = (const float*)d_in[6];
    const float* dWih0 = (const float*)d_in[7];
    const float* dWhh0 = (const float*)d_in[8];
    const float* dB0   = (const float*)d_in[9];
    const float* dWih1 = (const float*)d_in[10];
    const float* dWhh1 = (const float*)d_in[11];
    const float* dB1   = (const float*)d_in[12];
    const float* linW  = (const float*)d_in[13];
    const float* linb  = (const float*)d_in[14];
    float* out = (float*)d_out;
    char* ws = (char*)d_ws;

    float* predG = (float*)(ws + WS_PRED);
    u32*   barr  = (u32*)(ws + WS_BAR);
    u16*   hbp   = (u16*)(ws + WS_H);

    init_ws6<<<dim3(2048), dim3(256), 0, stream>>>(ws);
    (void)hipFuncSetAttribute((const void*)lstm_v6,
                              hipFuncAttributeMaxDynamicSharedMemorySize, L_TOT);
    lstm_v6<<<dim3(256), dim3(NTH), L_TOT, stream>>>(
        x, eWih0, eWhh0, eB0, eWih1, eWhh1, eB1,
        dWih0, dWhh0, dB0, dWih1, dWhh1, dB1,
        linW, linb, hbp, predG, barr, out);
}

// Round 7
// 42646.753 us; speedup vs baseline: 6.9016x; 6.9016x over previous
//
#include <hip/hip_runtime.h>
#include <math.h>

typedef unsigned short u16;
typedef unsigned int   u32;
typedef __attribute__((ext_vector_type(8))) short short8;
typedef __attribute__((ext_vector_type(4))) float f32x4;

#define SEQT 128
#define NOUT 64
#define NTH  512
#define MATU (800*224)

// ---- workspace offsets (bytes) ----
#define WS_W   0                 // 12 bf16 planes [800][224]: 4,300,800
#define WS_H1  4300800           // h1 plane [4096][200] u32: 3,276,800
#define WS_H2  7577600           // h2 plane: 3,276,800
#define WS_BAR 10854400          // 64 groups * 32 u32: 8192
#define WS_END 10862592          // < 13,125,888 proven ws floor

// ---- LDS offsets (bytes) ----
#define L_AHI  0                 // A hi plane [64][224] u16: 28672
#define L_ALO  28672             // A lo plane: 28672
#define L_G1   57344             // gates1 [64][200] f32: 51200
#define L_G2   108544            // gates2: 51200
#define L_PART 159744            // pred partials [64][8] f32: 2048
#define L_PRED 161792            // predL [64] f32: 256
#define L_TOT  162048            // <= 163840

// ---------------- helpers ----------------
__device__ __forceinline__ float fsig(float v) {
    return __builtin_amdgcn_rcpf(1.0f + __expf(-v));
}
__device__ __forceinline__ float ftanh(float v) {
    return 1.0f - 2.0f * __builtin_amdgcn_rcpf(__expf(2.0f * v) + 1.0f);
}
__device__ __forceinline__ u16 bf16_rne(float v) {
    u32 u = __float_as_uint(v);
    u = u + 0x7FFFu + ((u >> 16) & 1u);
    return (u16)(u >> 16);
}

// ---------------- weight prep: fp32 W[800][200] -> bf16 hi/lo [800][224] ----------------
__global__ void prep_weights(const float* __restrict__ s0, const float* __restrict__ s1,
                             const float* __restrict__ s2, const float* __restrict__ s3,
                             const float* __restrict__ s4, const float* __restrict__ s5,
                             u16* __restrict__ ws) {
    const float* src;
    int m = blockIdx.y;
    switch (m) {
        case 0: src = s0; break;
        case 1: src = s1; break;
        case 2: src = s2; break;
        case 3: src = s3; break;
        case 4: src = s4; break;
        default: src = s5; break;
    }
    int i = blockIdx.x * blockDim.x + threadIdx.x;
    int n = i / 224;
    int k = i - n * 224;
    float v = (k < 200) ? src[n * 200 + k] : 0.0f;
    u16 hi = bf16_rne(v);
    float rem = v - __uint_as_float(((u32)hi) << 16);
    u16 lo = bf16_rne(rem);
    ws[(size_t)(2 * m) * MATU + i]     = hi;
    ws[(size_t)(2 * m + 1) * MATU + i] = lo;
}

__global__ void init_v7(char* __restrict__ ws) {
    u32* p = (u32*)(ws + WS_H1);
    size_t n = (WS_END - WS_H1) / 4;
    size_t str = (size_t)gridDim.x * blockDim.x;
    for (size_t i = (size_t)blockIdx.x * blockDim.x + threadIdx.x; i < n; i += str)
        p[i] = 0u;
}

// ---------------- quad barrier (4 WGs) ----------------
__device__ __forceinline__ void gbar4(u32* barr, int g, unsigned& mygen) {
    __syncthreads();
    if (threadIdx.x == 0) {
        u32* cnt = barr + g * 32;
        u32* gen = barr + g * 32 + 16;
        unsigned target = mygen + 1;
        __threadfence();
        unsigned old = __hip_atomic_fetch_add(cnt, 1u, __ATOMIC_ACQ_REL, __HIP_MEMORY_SCOPE_AGENT);
        if (old == 3u) {
            __hip_atomic_store(cnt, 0u, __ATOMIC_RELAXED, __HIP_MEMORY_SCOPE_AGENT);
            __hip_atomic_fetch_add(gen, 1u, __ATOMIC_RELEASE, __HIP_MEMORY_SCOPE_AGENT);
        } else {
            while (__hip_atomic_load(gen, __ATOMIC_ACQUIRE, __HIP_MEMORY_SCOPE_AGENT) < target)
                __builtin_amdgcn_s_sleep(2);
        }
        __threadfence();
    }
    __syncthreads();
    mygen += 1;
}

// ---------------- stage h plane (u32 packed) -> LDS hi/lo bf16 planes ----------------
__device__ __forceinline__ void stageA(const u32* __restrict__ H, int g,
                                       u16* AhiL, u16* AloL, int tid) {
#pragma unroll
    for (int r = 0; r < 7; ++r) {
        int idx = tid + r * NTH;            // 0..3583 (= 64 rows * 56 col-quads)
        int row = idx / 56, cq = idx - row * 56;
        u32 v0 = 0, v1 = 0, v2 = 0, v3 = 0;
        if (cq < 50) {
            const uint4 vv = *(const uint4*)(H + (size_t)(g * 64 + row) * 200 + cq * 4);
            v0 = vv.x; v1 = vv.y; v2 = vv.z; v3 = vv.w;
        }
        ushort4 hi = {(u16)(v0 >> 16), (u16)(v1 >> 16), (u16)(v2 >> 16), (u16)(v3 >> 16)};
        ushort4 lo = {(u16)(v0 & 0xffff), (u16)(v1 & 0xffff), (u16)(v2 & 0xffff), (u16)(v3 & 0xffff)};
        *(ushort4*)(AhiL + row * 224 + cq * 4) = hi;
        *(ushort4*)(AloL + row * 224 + cq * 4) = lo;
    }
}

// ---------------- B fragments for one 16-row N-tile (compile-time c indexing) ----------------
__device__ __forceinline__ void loadBf(short8* Bh, short8* Bl,
        const u16* __restrict__ Whi, const u16* __restrict__ Wlo,
        int nt, int s, int lane) {
    int r = nt * 16 + (lane & 15);          // 0..207
    int q = r / 50;
    int j = r - q * 50;
    int n = (r < 200) ? (q * 200 + s * 50 + j) : 0;
    const u16* ph = Whi + (size_t)n * 224 + ((lane >> 4) << 3);
    const u16* pl = Wlo + (size_t)n * 224 + ((lane >> 4) << 3);
#pragma unroll
    for (int c = 0; c < 7; ++c) {
        Bh[c] = *(const short8*)(ph + c * 32);
        Bl[c] = *(const short8*)(pl + c * 32);
    }
}

// ---------------- one matmul pass: gates[64][slice-200cols] (+)= A(64xK) . W_slice^T ----------------
template<bool ACC>
__device__ __forceinline__ void run_pass(const u16* __restrict__ Whi, const u16* __restrict__ Wlo,
        const u16* AhiL, const u16* AloL, float* gbuf, int s, int lane, int w) {
    const int mhalf = w >> 2, ngrp = w & 3;
    const int ntcnt = (ngrp == 0) ? 4 : 3;   // 13 N-tiles split {0,4,8,12},{1,5,9},{2,6,10},{3,7,11}
    short8 a[2][7][2];
#pragma unroll
    for (int m = 0; m < 2; ++m)
#pragma unroll
        for (int c = 0; c < 7; ++c) {
            int row = (mhalf * 2 + m) * 16 + (lane & 15);
            int k0 = c * 32 + ((lane >> 4) << 3);
            a[m][c][0] = *(const short8*)(AhiL + row * 224 + k0);
            a[m][c][1] = *(const short8*)(AloL + row * 224 + k0);
        }
    short8 Bh[2][7], Bl[2][7];
    loadBf(Bh[0], Bl[0], Whi, Wlo, ngrp, s, lane);
    f32x4 acc[2][4];
#pragma unroll
    for (int m = 0; m < 2; ++m)
#pragma unroll
        for (int k = 0; k < 4; ++k) acc[m][k] = (f32x4){0.f, 0.f, 0.f, 0.f};
#pragma unroll
    for (int k = 0; k < 4; ++k) {
        if (k < ntcnt) {
            if (k + 1 < ntcnt)
                loadBf(Bh[(k + 1) & 1], Bl[(k + 1) & 1], Whi, Wlo, ngrp + 4 * (k + 1), s, lane);
#pragma unroll
            for (int c = 0; c < 7; ++c)
#pragma unroll
                for (int m = 0; m < 2; ++m) {
                    acc[m][k] = __builtin_amdgcn_mfma_f32_16x16x32_bf16(a[m][c][0], Bh[k & 1][c], acc[m][k], 0, 0, 0);
                    acc[m][k] = __builtin_amdgcn_mfma_f32_16x16x32_bf16(a[m][c][0], Bl[k & 1][c], acc[m][k], 0, 0, 0);
                    acc[m][k] = __builtin_amdgcn_mfma_f32_16x16x32_bf16(a[m][c][1], Bh[k & 1][c], acc[m][k], 0, 0, 0);
                }
        }
    }
#pragma unroll
    for (int k = 0; k < 4; ++k) {
        if (k < ntcnt) {
            int col = (ngrp + 4 * k) * 16 + (lane & 15);
            if (col < 200) {
#pragma unroll
                for (int m = 0; m < 2; ++m) {
                    int r0 = (mhalf * 2 + m) * 16 + ((lane >> 4) << 2);
#pragma unroll
                    for (int j = 0; j < 4; ++j) {
                        float* p = gbuf + (r0 + j) * 200 + col;
                        if (ACC) *p += acc[m][k][j]; else *p = acc[m][k][j];
                    }
                }
            }
        }
    }
}

// ---------------- elementwise (3200 items: 64 rows x 50 hid of this slice) ----------------
__device__ __forceinline__ void ew_phase(const float* gbuf, float* cst, u32* __restrict__ Hdst,
        const float* __restrict__ bias, const float* __restrict__ wih,
        const float* xsrc, int xstr, int s, int g, int tid) {
#pragma unroll
    for (int r = 0; r < 7; ++r) {
        int idx = tid + r * NTH;
        if (idx < 3200) {
            int row = idx / 50, i = idx - row * 50;
            float xv = 0.f;
            if (wih) xv = xsrc[row * xstr];
            float v[4];
#pragma unroll
            for (int q = 0; q < 4; ++q) {
                int n = q * 200 + s * 50 + i;
                float t = gbuf[row * 200 + q * 50 + i] + bias[n];
                if (wih) t = fmaf(xv, wih[n], t);
                v[q] = t;
            }
            float cn = fsig(v[1]) * cst[r] + fsig(v[0]) * ftanh(v[2]);
            cst[r] = cn;
            float h = fsig(v[3]) * ftanh(cn);
            u16 hi = bf16_rne(h);
            float rem = h - __uint_as_float(((u32)hi) << 16);
            u16 lo = bf16_rne(rem);
            Hdst[(size_t)(g * 64 + row) * 200 + s * 50 + i] = (((u32)hi) << 16) | lo;
        }
    }
}

// ---------------- decoder prediction (own 64 rows; local predL) ----------------
__device__ __forceinline__ void pred_phase(const u32* __restrict__ H2, float* part, float* predL,
        const float* __restrict__ linW, const float* __restrict__ linb,
        float* __restrict__ out, int sd, int g, int tid) {
    int row = tid >> 3, seg = tid & 7;
    const u32* p = H2 + (size_t)(g * 64 + row) * 200 + seg * 25;
    float acc = 0.f;
#pragma unroll
    for (int kk = 0; kk < 25; ++kk) {
        u32 v = p[kk];
        float h = __uint_as_float(v & 0xffff0000u) + __uint_as_float(v << 16);
        acc = fmaf(h, linW[seg * 25 + kk], acc);
    }
    part[row * 8 + seg] = acc;
    __syncthreads();
    if (tid < 64) {
        float psum = linb[0];
#pragma unroll
        for (int q = 0; q < 8; ++q) psum += part[tid * 8 + q];
        predL[tid] = psum;
        out[(size_t)(g * 64 + tid) * NOUT + sd] = psum;
    }
    __syncthreads();
}

// ---------------- main persistent kernel: 256 WGs = 64 batch-groups x 4 N-slices ----------------
__global__ __launch_bounds__(NTH, 2)
void lstm_v7(const float* __restrict__ x,
             const float* __restrict__ eWih0, const float* __restrict__ eB0,
             const float* __restrict__ eB1,
             const float* __restrict__ dWih0, const float* __restrict__ dB0,
             const float* __restrict__ dB1,
             const float* __restrict__ linW, const float* __restrict__ linb,
             const u16* __restrict__ wst, u32* H1, u32* H2, u32* barr,
             float* __restrict__ out) {
    extern __shared__ char sm[];
    u16* AhiL = (u16*)(sm + L_AHI);
    u16* AloL = (u16*)(sm + L_ALO);
    float* g1 = (float*)(sm + L_G1);
    float* g2 = (float*)(sm + L_G2);
    float* part = (float*)(sm + L_PART);
    float* predL = (float*)(sm + L_PRED);

    const int tid = threadIdx.x, lane = tid & 63, w = tid >> 6;
    const int g = blockIdx.x & 63, s = blockIdx.x >> 6;   // quad members differ by 64 -> same XCD under RR
    unsigned mygen = 0;

    const u16* eWhh0h = wst;              const u16* eWhh0l = wst + MATU;
    const u16* eWih1h = wst + 2 * MATU;   const u16* eWih1l = wst + 3 * MATU;
    const u16* eWhh1h = wst + 4 * MATU;   const u16* eWhh1l = wst + 5 * MATU;
    const u16* dWhh0h = wst + 6 * MATU;   const u16* dWhh0l = wst + 7 * MATU;
    const u16* dWih1h = wst + 8 * MATU;   const u16* dWih1l = wst + 9 * MATU;
    const u16* dWhh1h = wst + 10 * MATU;  const u16* dWhh1l = wst + 11 * MATU;

    float c1[7], c2[7];
#pragma unroll
    for (int r = 0; r < 7; ++r) { c1[r] = 0.f; c2[r] = 0.f; }

    // ---------------- encoder: 128 steps ----------------
    for (int t = 0; t < SEQT; ++t) {
        // phase 1: pass2 = h2(t-1) . Whh1^T  -> gates2 (store)
        stageA(H2, g, AhiL, AloL, tid);
        __syncthreads();
        run_pass<false>(eWhh1h, eWhh1l, AhiL, AloL, g2, s, lane, w);
        __syncthreads();
        // phase 2: stage A1 = h1(t-1)
        stageA(H1, g, AhiL, AloL, tid);
        __syncthreads();
        gbar4(barr, g, mygen);          // barS: all quads done reading h1(t-1), h2(t-1)
        // phase 4: l1 = h1(t-1) . Whh0^T -> gates1; ew1 (+x) -> publish h1(t) in place
        run_pass<false>(eWhh0h, eWhh0l, AhiL, AloL, g1, s, lane, w);
        __syncthreads();
        ew_phase(g1, c1, H1, eB0, eWih0, x + (size_t)(g * 64) * SEQT + t, SEQT, s, g, tid);
        gbar4(barr, g, mygen);          // bar1: h1(t) published
        // phase 5: pass1 = h1(t) . Wih1^T -> gates2 (+=); ew2 -> publish h2(t)
        stageA(H1, g, AhiL, AloL, tid);
        __syncthreads();
        run_pass<true>(eWih1h, eWih1l, AhiL, AloL, g2, s, lane, w);
        __syncthreads();
        ew_phase(g2, c2, H2, eB1, nullptr, nullptr, 0, s, g, tid);
        gbar4(barr, g, mygen);          // bar2: h2(t) published
    }

    // decoder init: pred(-1) = x[:,127]
    if (tid < 64) predL[tid] = x[(size_t)(g * 64 + tid) * SEQT + (SEQT - 1)];
    __syncthreads();

    // ---------------- decoder: 64 steps ----------------
    for (int sd = 0; sd < NOUT; ++sd) {
        stageA(H2, g, AhiL, AloL, tid);
        __syncthreads();
        run_pass<false>(dWhh1h, dWhh1l, AhiL, AloL, g2, s, lane, w);
        __syncthreads();
        stageA(H1, g, AhiL, AloL, tid);
        __syncthreads();
        gbar4(barr, g, mygen);          // barS
        run_pass<false>(dWhh0h, dWhh0l, AhiL, AloL, g1, s, lane, w);
        __syncthreads();
        ew_phase(g1, c1, H1, dB0, dWih0, (const float*)predL, 1, s, g, tid);
        gbar4(barr, g, mygen);          // bar1
        stageA(H1, g, AhiL, AloL, tid);
        __syncthreads();
        run_pass<true>(dWih1h, dWih1l, AhiL, AloL, g2, s, lane, w);
        __syncthreads();
        ew_phase(g2, c2, H2, dB1, nullptr, nullptr, 0, s, g, tid);
        gbar4(barr, g, mygen);          // bar2: h2(sd) published
        pred_phase(H2, part, predL, linW, linb, out, sd, g, tid);
        // no extra barrier: peers' next overwrite of H2 is gated behind bar1(sd+1)
    }
}

extern "C" void kernel_launch(void* const* d_in, const int* in_sizes, int n_in,
                              void* d_out, int out_size, void* d_ws, size_t ws_size,
                              hipStream_t stream) {
    const float* x     = (const float*)d_in[0];
    const float* eWih0 = (const float*)d_in[1];
    const float* eWhh0 = (const float*)d_in[2];
    const float* eB0   = (const float*)d_in[3];
    const float* eWih1 = (const float*)d_in[4];
    const float* eWhh1 = (const float*)d_in[5];
    const float* eB1   = (const float*)d_in[6];
    const float* dWih0 = (const float*)d_in[7];
    const float* dWhh0 = (const float*)d_in[8];
    const float* dB0   = (const float*)d_in[9];
    const float* dWih1 = (const float*)d_in[10];
    const float* dWhh1 = (const float*)d_in[11];
    const float* dB1   = (const float*)d_in[12];
    const float* linW  = (const float*)d_in[13];
    const float* linb  = (const float*)d_in[14];
    float* out = (float*)d_out;
    char* ws = (char*)d_ws;

    u16* wst  = (u16*)(ws + WS_W);
    u32* H1   = (u32*)(ws + WS_H1);
    u32* H2   = (u32*)(ws + WS_H2);
    u32* barr = (u32*)(ws + WS_BAR);

    prep_weights<<<dim3(MATU / 256, 6), 256, 0, stream>>>(
        eWhh0, eWih1, eWhh1, dWhh0, dWih1, dWhh1, wst);
    init_v7<<<dim3(512), dim3(256), 0, stream>>>(ws);

    (void)hipFuncSetAttribute((const void*)lstm_v7,
                              hipFuncAttributeMaxDynamicSharedMemorySize, L_TOT);
    lstm_v7<<<dim3(256), dim3(NTH), L_TOT, stream>>>(
        x, eWih0, eB0, eB1, dWih0, dB0, dB1, linW, linb,
        wst, H1, H2, barr, out);
}